// Round 19
// baseline (1129.454 us; speedup 1.0000x reference)
//
#include <hip/hip_runtime.h>
#include <math.h>

#define N_NODES 50000
#define N_EDGES 500000
#define SCAN_NB ((N_NODES + 1023) / 1024)

using bf16x8 = __attribute__((ext_vector_type(8))) short;
using f32x4  = __attribute__((ext_vector_type(4))) float;

// ---------- bf16 helpers ----------
__device__ inline float b2f(unsigned short u) {
  union { unsigned int i; float f; } v; v.i = ((unsigned int)u) << 16; return v.f;
}
__device__ inline unsigned short f2b(float f) {
  union { float f; unsigned int i; } v; v.f = f;
  unsigned int x = v.i;
  return (unsigned short)((x + 0x7fffu + ((x >> 16) & 1u)) >> 16);
}
__device__ inline unsigned int pk2(float a, float b) {
  return (unsigned int)f2b(a) | ((unsigned int)f2b(b) << 16);
}
__device__ inline void stv(unsigned short* p, float v) { *p = f2b(v); }
__device__ inline void stv(float* p, float v) { *p = v; }
__host__ __device__ inline int imin(int a, int b) { return a < b ? a : b; }

// direct global->LDS DMA, 16B per lane; lds base is wave-uniform, lane offset = lane*16
__device__ inline void gload16(const unsigned short* g, unsigned short* l) {
  __builtin_amdgcn_global_load_lds((const __attribute__((address_space(1))) unsigned int*)g,
                                   (__attribute__((address_space(3))) unsigned int*)l, 16, 0, 0);
}

// ---------------- degree / CSR ----------------
__global__ void k_count(const int* __restrict__ src, const int* __restrict__ dst,
                        int* __restrict__ cnt, int* __restrict__ degall) {
  int e = blockIdx.x * blockDim.x + threadIdx.x;
  if (e < N_EDGES) {
    atomicAdd(&cnt[dst[e]], 1);
    atomicAdd(&degall[src[e]], 1);
    atomicAdd(&degall[dst[e]], 1);
  }
}

// scan phase 1: block-local exclusive scan, block totals -> sums
__global__ __launch_bounds__(1024) void k_scan1(const int* __restrict__ cnt, int* __restrict__ ptr,
                                                int* __restrict__ sums) {
  __shared__ int buf[1024];
  int i = blockIdx.x * 1024 + threadIdx.x;
  int v = (i < N_NODES) ? cnt[i] : 0;
  buf[threadIdx.x] = v;
  __syncthreads();
  for (int off = 1; off < 1024; off <<= 1) {
    int tv = (threadIdx.x >= off) ? buf[threadIdx.x - off] : 0;
    __syncthreads();
    buf[threadIdx.x] += tv;
    __syncthreads();
  }
  if (i < N_NODES) ptr[i] = buf[threadIdx.x] - v;
  if (threadIdx.x == 1023) sums[blockIdx.x] = buf[1023];
}

// scan phase 2 (merged): each block prefix-sums block totals itself
__global__ __launch_bounds__(1024) void k_scan3(int* __restrict__ ptr, const int* __restrict__ sums) {
  __shared__ int soff;
  if (threadIdx.x == 0) {
    int acc = 0;
    for (int b = 0; b < (int)blockIdx.x; b++) acc += sums[b];
    soff = acc;
  }
  __syncthreads();
  int i = blockIdx.x * 1024 + threadIdx.x;
  if (i < N_NODES) ptr[i] += soff;
  if (blockIdx.x == SCAN_NB - 1 && threadIdx.x == 1023) ptr[N_NODES] = soff + sums[SCAN_NB - 1];
}

__global__ void k_fill(const int* __restrict__ src, const int* __restrict__ dst,
                       const int* __restrict__ ptr, int* __restrict__ cnt, int* __restrict__ col) {
  int e = blockIdx.x * blockDim.x + threadIdx.x;
  if (e < N_EDGES) {
    int d = dst[e];
    int pos = atomicAdd(&cnt[d], 1);
    col[ptr[d] + pos] = src[e];
  }
}

__global__ void k_avglog(const int* __restrict__ degall, float* __restrict__ scal) {
  __shared__ float L[256];
  float s = 0.f;
  for (int n = blockIdx.x * blockDim.x + threadIdx.x; n < N_NODES; n += gridDim.x * blockDim.x)
    s += logf((float)degall[n] + 1.0f);
  L[threadIdx.x] = s;
  __syncthreads();
  for (int o = 128; o > 0; o >>= 1) {
    if (threadIdx.x < o) L[threadIdx.x] += L[threadIdx.x + o];
    __syncthreads();
  }
  if (threadIdx.x == 0) atomicAdd(&scal[0], L[0]);
}

// avg folded in: avg = scal[0]/N
__global__ void k_scalars(const int* __restrict__ ptr, const float* __restrict__ scal,
                          float* __restrict__ a_arr, float* __restrict__ c_arr) {
  int n = blockIdx.x * blockDim.x + threadIdx.x;
  if (n < N_NODES) {
    float avg = scal[0] / (float)N_NODES;
    int d = ptr[n + 1] - ptr[n];
    float degc = fmaxf((float)d, 1.f);
    float logd = logf(degc + 1.f);
    a_arr[n] = logd / avg;
    c_arr[n] = avg / logd;
  }
}

// vectorized cast: 4 f32 -> 4 bf16 per thread
__global__ void k_cast(const float* __restrict__ x, unsigned short* __restrict__ xb, int total4) {
  int i = blockIdx.x * blockDim.x + threadIdx.x;
  if (i < total4) {
    float4 v = *(const float4*)(x + i * 4);
    *(uint2*)(xb + i * 4) = make_uint2(pk2(v.x, v.y), pk2(v.z, v.w));
  }
}

// merged weight prep: wpreT (transpose-cast), biasPre, bcomb
__global__ void k_wprep(const float* __restrict__ Wpre, const float* __restrict__ bpre,
                        const float* __restrict__ bpost, const float* __restrict__ Wlin,
                        const float* __restrict__ blin,
                        unsigned short* __restrict__ wpreT, float* __restrict__ biasPre,
                        float* __restrict__ bcomb, int F, int FO) {
  int i = blockIdx.x * blockDim.x + threadIdx.x;
  if (i < 2 * F * F) {
    int j = i / F, k = i % F;
    float v = (j < F) ? Wpre[(size_t)k * F + j] : Wpre[(size_t)(F + k) * F + (j - F)];
    wpreT[i] = f2b(v);
  }
  if (i < 2 * F) biasPre[i] = (i < F) ? bpre[i] : 0.f;
  if (i < FO) {
    float acc = blin[i];
    for (int k = 0; k < FO; k++) acc += bpost[k] * Wlin[k * FO + i];
    bcomb[i] = acc;
  }
}

// ---------------- weight GEMM: CT[c][r] = bf16( (Wpost@Wlin)[r][c] ) ----------------
__global__ __launch_bounds__(256) void k_wcombT(const float* __restrict__ A, const float* __restrict__ B,
                                                unsigned short* __restrict__ CT, int M, int Ncol, int K) {
  __shared__ float As[16][136];
  __shared__ float Bs[16][128];
  int tid = threadIdx.x;
  int row0 = blockIdx.y * 128, col0 = blockIdx.x * 128;
  int am = tid >> 1, ah = (tid & 1) * 8;
  int ty = tid >> 4, tx = tid & 15;
  float acc[8][8];
#pragma unroll
  for (int i = 0; i < 8; i++)
#pragma unroll
    for (int j = 0; j < 8; j++) acc[i][j] = 0.f;
  int arow = row0 + am;
  bool av = arow < M;
  const float* Ar = A + (size_t)arow * K;
  for (int k0 = 0; k0 < K; k0 += 16) {
    float4 a0 = make_float4(0, 0, 0, 0), a1 = make_float4(0, 0, 0, 0);
    if (av) {
      a0 = *(const float4*)(Ar + k0 + ah);
      a1 = *(const float4*)(Ar + k0 + ah + 4);
    }
    As[ah + 0][am] = a0.x; As[ah + 1][am] = a0.y; As[ah + 2][am] = a0.z; As[ah + 3][am] = a0.w;
    As[ah + 4][am] = a1.x; As[ah + 5][am] = a1.y; As[ah + 6][am] = a1.z; As[ah + 7][am] = a1.w;
#pragma unroll
    for (int i = 0; i < 2; i++) {
      int q = tid * 2 + i;
      int kk = q >> 5, j4 = (q & 31) * 4;
      int bc = col0 + j4;
      float4 b = make_float4(0, 0, 0, 0);
      if (bc < Ncol && (k0 + kk) < K) b = *(const float4*)(B + (size_t)(k0 + kk) * Ncol + bc);
      *(float4*)(&Bs[kk][j4]) = b;
    }
    __syncthreads();
#pragma unroll
    for (int kk = 0; kk < 16; kk++) {
      float av8[8], bv8[8];
#pragma unroll
      for (int i = 0; i < 8; i++) av8[i] = As[kk][ty * 8 + i];
#pragma unroll
      for (int j = 0; j < 8; j++) bv8[j] = Bs[kk][tx * 8 + j];
#pragma unroll
      for (int i = 0; i < 8; i++)
#pragma unroll
        for (int j = 0; j < 8; j++) acc[i][j] = fmaf(av8[i], bv8[j], acc[i][j]);
    }
    __syncthreads();
  }
#pragma unroll
  for (int i = 0; i < 8; i++) {
    int r = row0 + ty * 8 + i;
    if (r < M) {
#pragma unroll
      for (int j = 0; j < 8; j++) {
        int c = col0 + tx * 8 + j;
        if (c < Ncol) CT[(size_t)c * M + r] = f2b(acc[i][j]);
      }
    }
  }
}

// ---------------- m97-style MFMA GEMM (pre-GEMM): 128x128 tile, BK=32 ----------------
template <typename To>
__global__ __launch_bounds__(256) void k_mm(
    const unsigned short* __restrict__ A, int K,
    const unsigned short* __restrict__ BT,
    const float* __restrict__ bias,
    To* __restrict__ C, int n0, int M, int Ncol) {
  __shared__ unsigned short lds[2][2][4096];
  const int tid = threadIdx.x;
  const int lane = tid & 63;
  const int wid = tid >> 6;
  const int wr = wid >> 1, wc = wid & 1;
  const int row0 = blockIdx.y * 128;
  const int col0 = blockIdx.x * 128;
  const int l15 = lane & 15, lq = lane >> 4;
  const int srow = wid * 32 + (lane >> 2);
  const int scol = (lane & 3) * 8;
  const unsigned short* gA0 = A + (size_t)imin(row0 + srow, N_NODES - 1) * K + scol;
  const unsigned short* gA1 = A + (size_t)imin(row0 + srow + 16, N_NODES - 1) * K + scol;
  const unsigned short* gB0 = BT + (size_t)(col0 + srow) * K + scol;
  const unsigned short* gB1 = BT + (size_t)(col0 + srow + 16) * K + scol;

  f32x4 acc[4][4];
#pragma unroll
  for (int m = 0; m < 4; m++)
#pragma unroll
    for (int n = 0; n < 4; n++) acc[m][n] = (f32x4){0.f, 0.f, 0.f, 0.f};

  auto stage = [&](int buf, int k0) {
    gload16(gA0 + k0, &lds[buf][0][wid * 1024]);
    gload16(gA1 + k0, &lds[buf][0][wid * 1024 + 512]);
    gload16(gB0 + k0, &lds[buf][1][wid * 1024]);
    gload16(gB1 + k0, &lds[buf][1][wid * 1024 + 512]);
  };

  const int nk = K / 32;
  stage(0, 0);
  __syncthreads();
  for (int t = 0; t < nk; ++t) {
    const int cur = t & 1;
    if (t + 1 < nk) stage(cur ^ 1, (t + 1) * 32);
    bf16x8 a[4], b[4];
#pragma unroll
    for (int m = 0; m < 4; m++)
      a[m] = *(const bf16x8*)&lds[cur][0][(wr * 64 + m * 16 + l15) * 32 + lq * 8];
#pragma unroll
    for (int n = 0; n < 4; n++)
      b[n] = *(const bf16x8*)&lds[cur][1][(wc * 64 + n * 16 + l15) * 32 + lq * 8];
#pragma unroll
    for (int m = 0; m < 4; m++)
#pragma unroll
      for (int n = 0; n < 4; n++)
        acc[m][n] = __builtin_amdgcn_mfma_f32_16x16x32_bf16(a[m], b[n], acc[m][n], 0, 0, 0);
    __syncthreads();
  }
#pragma unroll
  for (int n = 0; n < 4; n++) {
    int col = col0 + wc * 64 + n * 16 + l15;
    float bv = bias ? bias[col] : 0.f;
#pragma unroll
    for (int m = 0; m < 4; m++) {
#pragma unroll
      for (int j = 0; j < 4; j++) {
        int r = row0 + wr * 64 + m * 16 + lq * 4 + j;
        if (r < M) stv(&C[(size_t)(n0 + r) * Ncol + col], acc[m][n][j] + bv);
      }
    }
  }
}

// ---------------- post-GEMM: virtual 13F A, CHUNK-MAJOR region walk, fused BN stats ----------------
// 64xNTILE tile, BK=64, XOR-swizzled LDS. Per G-chunk: 3 consecutive steps (B slices
// W2/W3/W4, A chunk L2-hot) into acc0/1/2. Epilogue: o = acc0 + an*acc1 + cn*acc2 + bias;
// if STATS: per-column sum/sumsq reduced via shfl over lq, one atomicAdd pair per (wave,col).
template <int NTILE, int F, typename To, bool STATS>
__global__ __launch_bounds__(256, 2) void k_mmP(
    const unsigned short* __restrict__ X,
    const unsigned short* __restrict__ G,
    const float* __restrict__ a_arr, const float* __restrict__ c_arr,
    const unsigned short* __restrict__ BT,
    const float* __restrict__ bias,
    To* __restrict__ C, float* __restrict__ gsum, float* __restrict__ gsq,
    int n0, int M, int Mbuf, int Ncol) {
  constexpr int K13 = 13 * F;
  constexpr int F4 = 4 * F;
  constexpr int SX = F / 64;
  constexpr int NG = F4 / 64;
  constexpr int NS = SX + 3 * NG;
  constexpr int CB = NTILE / 32;
  constexpr int NF = NTILE / 32;
  __shared__ unsigned short lds[2][(64 + NTILE) * 64];
  const int tid = threadIdx.x;
  const int lane = tid & 63;
  const int wid = tid >> 6;
  const int wr = wid >> 1, wc = wid & 1;
  const int row0 = blockIdx.y * 64;
  const int col0 = blockIdx.x * NTILE;
  const int l15 = lane & 15, lq = lane >> 4;
  const int lr8 = lane >> 3;
  const int lc8 = lane & 7;

  f32x4 acc0[2][NF], acc1[2][NF], acc2[2][NF];
#pragma unroll
  for (int m = 0; m < 2; m++)
#pragma unroll
    for (int n = 0; n < NF; n++) {
      acc0[m][n] = (f32x4){0.f, 0.f, 0.f, 0.f};
      acc1[m][n] = (f32x4){0.f, 0.f, 0.f, 0.f};
      acc2[m][n] = (f32x4){0.f, 0.f, 0.f, 0.f};
    }

  auto stage = [&](int buf, int s) {
    unsigned short* Ar = &lds[buf][0];
    unsigned short* Br = &lds[buf][64 * 64];
    int koff, akoff;
    bool isx = (s < SX);
    if (isx) {
      koff = s * 64;
      akoff = s * 64;
    } else {
      int q = s - SX;
      int tg = q / 3;
      int reg = q - 3 * tg;
      koff = F + reg * F4 + tg * 64;
      akoff = tg * 64;
    }
#pragma unroll
    for (int c = 0; c < 2; c++) {
      int r = (wid * 2 + c) * 8 + lr8;
      int gc = (lc8 ^ (r & 7)) * 8;
      const unsigned short* src;
      if (isx)
        src = X + (size_t)imin(n0 + row0 + r, N_NODES - 1) * F + akoff + gc;
      else
        src = G + (size_t)imin(row0 + r, Mbuf - 1) * F4 + akoff + gc;
      gload16(src, Ar + (wid * 2 + c) * 512);
    }
#pragma unroll
    for (int c = 0; c < CB; c++) {
      int r = (wid * CB + c) * 8 + lr8;
      int gc = (lc8 ^ (r & 7)) * 8;
      gload16(BT + (size_t)(col0 + r) * K13 + koff + gc, Br + (wid * CB + c) * 512);
    }
  };

  stage(0, 0);
  __syncthreads();
  for (int s = 0; s < NS; ++s) {
    const int cur = s & 1;
    if (s + 1 < NS) stage(cur ^ 1, s + 1);
    const unsigned short* Ar = &lds[cur][0];
    const unsigned short* Br = &lds[cur][64 * 64];
    bf16x8 a[2][2], b[2][NF];
#pragma unroll
    for (int ks = 0; ks < 2; ks++) {
#pragma unroll
      for (int m = 0; m < 2; m++) {
        int r = wr * 32 + m * 16 + l15;
        a[ks][m] = *(const bf16x8*)&Ar[r * 64 + ((lq + ks * 4) ^ (r & 7)) * 8];
      }
#pragma unroll
      for (int n = 0; n < NF; n++) {
        int r = wc * (NTILE / 2) + n * 16 + l15;
        b[ks][n] = *(const bf16x8*)&Br[r * 64 + ((lq + ks * 4) ^ (r & 7)) * 8];
      }
    }
    const int reg = (s < SX) ? 0 : (s - SX) % 3;
    if (reg == 0) {
#pragma unroll
      for (int ks = 0; ks < 2; ks++)
#pragma unroll
        for (int m = 0; m < 2; m++)
#pragma unroll
          for (int n = 0; n < NF; n++)
            acc0[m][n] = __builtin_amdgcn_mfma_f32_16x16x32_bf16(a[ks][m], b[ks][n], acc0[m][n], 0, 0, 0);
    } else if (reg == 1) {
#pragma unroll
      for (int ks = 0; ks < 2; ks++)
#pragma unroll
        for (int m = 0; m < 2; m++)
#pragma unroll
          for (int n = 0; n < NF; n++)
            acc1[m][n] = __builtin_amdgcn_mfma_f32_16x16x32_bf16(a[ks][m], b[ks][n], acc1[m][n], 0, 0, 0);
    } else {
#pragma unroll
      for (int ks = 0; ks < 2; ks++)
#pragma unroll
        for (int m = 0; m < 2; m++)
#pragma unroll
          for (int n = 0; n < NF; n++)
            acc2[m][n] = __builtin_amdgcn_mfma_f32_16x16x32_bf16(a[ks][m], b[ks][n], acc2[m][n], 0, 0, 0);
    }
    __syncthreads();
  }
  // epilogue: per-row an/cn combine + bias (+ fused column stats via shfl)
  float bs1[NF], bs2[NF];
#pragma unroll
  for (int n = 0; n < NF; n++) { bs1[n] = 0.f; bs2[n] = 0.f; }
#pragma unroll
  for (int m = 0; m < 2; m++) {
    f32x4 anv, cnv;
#pragma unroll
    for (int j = 0; j < 4; j++) {
      int g = imin(n0 + row0 + wr * 32 + m * 16 + lq * 4 + j, N_NODES - 1);
      anv[j] = a_arr[g];
      cnv[j] = c_arr[g];
    }
#pragma unroll
    for (int n = 0; n < NF; n++) {
      f32x4 v = acc0[m][n] + anv * acc1[m][n] + cnv * acc2[m][n];
      int col = col0 + wc * (NTILE / 2) + n * 16 + l15;
      float bv = bias[col];
#pragma unroll
      for (int j = 0; j < 4; j++) {
        int r = row0 + wr * 32 + m * 16 + lq * 4 + j;
        if (r < M) {
          float val = v[j] + bv;
          stv(&C[(size_t)(n0 + r) * Ncol + col], val);
          if (STATS) {
            bs1[n] += val;
            bs2[n] += val * val;
          }
        }
      }
    }
  }
  if (STATS) {
#pragma unroll
    for (int n = 0; n < NF; n++) {
      float a1 = bs1[n], a2 = bs2[n];
      a1 += __shfl_xor(a1, 16); a2 += __shfl_xor(a2, 16);
      a1 += __shfl_xor(a1, 32); a2 += __shfl_xor(a2, 32);
      if (lq == 0) {
        int col = col0 + wc * (NTILE / 2) + n * 16 + l15;
        atomicAdd(&gsum[col], a1);
        atomicAdd(&gsq[col], a2);
      }
    }
  }
}

// ---------------- edge aggregation (vectorized): writes 4F rows [mean | min | max | std] ----------------
template <int F>
__global__ __launch_bounds__(256) void k_edge_agg(
    const unsigned short* __restrict__ ts,
    const int* __restrict__ ptr, const int* __restrict__ col,
    unsigned short* __restrict__ aggc, int n0, int nchunk) {
  constexpr int VU = F / 128;
  int idx = (blockIdx.x * blockDim.x + threadIdx.x) >> 6;
  int lane = threadIdx.x & 63;
  if (idx >= nchunk) return;
  int n = n0 + idx;
  if (n >= N_NODES) return;
  float S1[2 * VU], S2[2 * VU], mn[2 * VU], mx[2 * VU];
#pragma unroll
  for (int u = 0; u < 2 * VU; u++) {
    S1[u] = 0.f; S2[u] = 0.f; mn[u] = 3.4e38f; mx[u] = -3.4e38f;
  }
  int e0 = ptr[n], e1 = ptr[n + 1];
  for (int e = e0; e < e1; ++e) {
    int sidx = col[e];
    const unsigned int* sr = (const unsigned int*)(ts + (size_t)sidx * 2 * F + F);
#pragma unroll
    for (int u = 0; u < VU; u++) {
      unsigned int v = sr[lane + 64 * u];
      float f0 = b2f((unsigned short)(v & 0xffff));
      float f1 = b2f((unsigned short)(v >> 16));
      S1[2 * u] += f0; S2[2 * u] += f0 * f0;
      mn[2 * u] = fminf(mn[2 * u], f0); mx[2 * u] = fmaxf(mx[2 * u], f0);
      S1[2 * u + 1] += f1; S2[2 * u + 1] += f1 * f1;
      mn[2 * u + 1] = fminf(mn[2 * u + 1], f1); mx[2 * u + 1] = fmaxf(mx[2 * u + 1], f1);
    }
  }
  int d = e1 - e0;
  const unsigned int* tr = (const unsigned int*)(ts + (size_t)n * 2 * F);
  unsigned int* ob = (unsigned int*)(aggc + (size_t)idx * 4 * F);
  constexpr int UB = 64 * VU;
#pragma unroll
  for (int u = 0; u < VU; u++) {
    int ui = lane + 64 * u;
    float mean0, mean1, lo0, lo1, hi0, hi1, sd0, sd1;
    if (d > 0) {
      float inv = 1.f / (float)d;
      unsigned int tv = tr[ui];
      float t0 = b2f((unsigned short)(tv & 0xffff));
      float t1 = b2f((unsigned short)(tv >> 16));
      float ms0 = S1[2 * u] * inv, ms1 = S1[2 * u + 1] * inv;
      sd0 = sqrtf(fmaxf(S2[2 * u] * inv - ms0 * ms0, 0.f) + 1e-5f);
      sd1 = sqrtf(fmaxf(S2[2 * u + 1] * inv - ms1 * ms1, 0.f) + 1e-5f);
      mean0 = t0 + ms0; mean1 = t1 + ms1;
      lo0 = t0 + mn[2 * u]; lo1 = t1 + mn[2 * u + 1];
      hi0 = t0 + mx[2 * u]; hi1 = t1 + mx[2 * u + 1];
    } else {
      mean0 = mean1 = lo0 = lo1 = hi0 = hi1 = 0.f;
      sd0 = sd1 = sqrtf(1e-5f);
    }
    unsigned int* o1 = ob + ui;
    o1[0] = pk2(mean0, mean1);
    o1[UB] = pk2(lo0, lo1);
    o1[2 * UB] = pk2(hi0, hi1);
    o1[3 * UB] = pk2(sd0, sd1);
  }
}

// ---------------- BN stats (f32 path, layer 4 only) ----------------
template <int FO>
__global__ __launch_bounds__(256) void k_bn_stats_f32(const float* __restrict__ o,
                                                      float* __restrict__ gsum, float* __restrict__ gsq) {
  constexpr int TOTAL = N_NODES * FO;
  float s1[4], s2[4];
#pragma unroll
  for (int j = 0; j < 4; j++) { s1[j] = 0.f; s2[j] = 0.f; }
  const int stride = gridDim.x * 1024;
  for (int base = blockIdx.x * 1024 + threadIdx.x * 4; base < TOTAL; base += stride) {
    float4 v = *(const float4*)(o + base);
    s1[0] += v.x; s2[0] += v.x * v.x;
    s1[1] += v.y; s2[1] += v.y * v.y;
    s1[2] += v.z; s2[2] += v.z * v.z;
    s1[3] += v.w; s2[3] += v.w * v.w;
  }
  __shared__ float L1[1024], L2[1024];
#pragma unroll
  for (int j = 0; j < 4; j++) {
    L1[threadIdx.x * 4 + j] = s1[j];
    L2[threadIdx.x * 4 + j] = s2[j];
  }
  __syncthreads();
  int c = threadIdx.x;
  if (c < FO) {
    float a1 = 0.f, a2 = 0.f;
    for (int i = c; i < 1024; i += FO) { a1 += L1[i]; a2 += L2[i]; }
    atomicAdd(&gsum[c], a1);
    atomicAdd(&gsq[c], a2);
  }
}

__global__ void k_bn_fin(const float* bnsum, const float* bnsq, float* bnmean, float* bnrs, int FO) {
  int c = threadIdx.x;
  if (c < FO) {
    float mean = bnsum[c] / (float)N_NODES;
    float var = bnsq[c] / (float)N_NODES - mean * mean;
    bnmean[c] = mean;
    bnrs[c] = rsqrtf(var + 1e-5f);
  }
}

// ---------------- BN+ELU (vectorized) ----------------
template <int FO>
__global__ __launch_bounds__(256) void k_bn_elu_bf(const unsigned short* __restrict__ o,
                                                   const float* __restrict__ mean, const float* __restrict__ rs,
                                                   const float* __restrict__ gamma, const float* __restrict__ beta,
                                                   unsigned short* __restrict__ h) {
  constexpr int TOTAL = N_NODES * FO;
  int base = (blockIdx.x * blockDim.x + threadIdx.x) * 8;
  if (base >= TOTAL) return;
  int c0 = base % FO;
  uint4 v = *(const uint4*)(o + base);
  const unsigned int* u = (const unsigned int*)&v;
  unsigned int outw[4];
#pragma unroll
  for (int w = 0; w < 4; w++) {
    int c = c0 + 2 * w;
    float f0 = b2f((unsigned short)(u[w] & 0xffff));
    float f1 = b2f((unsigned short)(u[w] >> 16));
    float y0 = gamma[c] * (f0 - mean[c]) * rs[c] + beta[c];
    float y1 = gamma[c + 1] * (f1 - mean[c + 1]) * rs[c + 1] + beta[c + 1];
    y0 = y0 > 0.f ? y0 : expm1f(y0);
    y1 = y1 > 0.f ? y1 : expm1f(y1);
    outw[w] = pk2(y0, y1);
  }
  *(uint4*)(h + base) = *(uint4*)outw;
}

template <int FO>
__global__ __launch_bounds__(256) void k_bn_elu_f32(const float* __restrict__ o,
                                                    const float* __restrict__ mean, const float* __restrict__ rs,
                                                    const float* __restrict__ gamma, const float* __restrict__ beta,
                                                    unsigned short* __restrict__ h, float* __restrict__ bnout) {
  constexpr int TOTAL = N_NODES * FO;
  int base = (blockIdx.x * blockDim.x + threadIdx.x) * 4;
  if (base >= TOTAL) return;
  int c = base % FO;
  float4 v = *(const float4*)(o + base);
  float y0 = gamma[c] * (v.x - mean[c]) * rs[c] + beta[c];
  float y1 = gamma[c + 1] * (v.y - mean[c + 1]) * rs[c + 1] + beta[c + 1];
  float y2 = gamma[c + 2] * (v.z - mean[c + 2]) * rs[c + 2] + beta[c + 2];
  float y3 = gamma[c + 3] * (v.w - mean[c + 3]) * rs[c + 3] + beta[c + 3];
  if (bnout) *(float4*)(bnout + base) = make_float4(y0, y1, y2, y3);
  unsigned int o0 = pk2(y0 > 0.f ? y0 : expm1f(y0), y1 > 0.f ? y1 : expm1f(y1));
  unsigned int o1 = pk2(y2 > 0.f ? y2 : expm1f(y2), y3 > 0.f ? y3 : expm1f(y3));
  *(uint2*)(h + base) = make_uint2(o0, o1);
}

// ---------------- misc ----------------
// vectorized add: 8 bf16 per thread
__global__ void k_add(const unsigned short* __restrict__ a, const unsigned short* __restrict__ b,
                      unsigned short* __restrict__ c) {
  int i = blockIdx.x * blockDim.x + threadIdx.x;
  if (i < (N_NODES * 128) / 8) {
    uint4 va = *(const uint4*)(a + i * 8);
    uint4 vb = *(const uint4*)(b + i * 8);
    const unsigned int* ua = (const unsigned int*)&va;
    const unsigned int* ub = (const unsigned int*)&vb;
    unsigned int outw[4];
#pragma unroll
    for (int w = 0; w < 4; w++) {
      float a0 = b2f((unsigned short)(ua[w] & 0xffff)) + b2f((unsigned short)(ub[w] & 0xffff));
      float a1 = b2f((unsigned short)(ua[w] >> 16)) + b2f((unsigned short)(ub[w] >> 16));
      outw[w] = pk2(a0, a1);
    }
    *(uint4*)(c + i * 8) = *(uint4*)outw;
  }
}

// vectorized logits: uint4 loads of h4 row
__global__ void k_logits(const unsigned short* __restrict__ h4, const float* __restrict__ Wc,
                         const float* __restrict__ bc, float* __restrict__ out) {
  int n = blockIdx.x * blockDim.x + threadIdx.x;
  if (n < N_NODES) {
    float acc0 = bc[0], acc1 = bc[1];
    const uint4* hr = (const uint4*)(h4 + (size_t)n * 64);
#pragma unroll
    for (int q = 0; q < 8; q++) {
      uint4 v = hr[q];
      const unsigned int* u = (const unsigned int*)&v;
#pragma unroll
      for (int w = 0; w < 4; w++) {
        int k = q * 8 + w * 2;
        float f0 = b2f((unsigned short)(u[w] & 0xffff));
        float f1 = b2f((unsigned short)(u[w] >> 16));
        acc0 += f0 * Wc[k * 2 + 0] + f1 * Wc[(k + 1) * 2 + 0];
        acc1 += f0 * Wc[k * 2 + 1] + f1 * Wc[(k + 1) * 2 + 1];
      }
    }
    out[n * 2 + 0] = acc0;
    out[n * 2 + 1] = acc1;
  }
}

// ---------------- driver ----------------
struct WS {
  int *ptr, *col, *cnt, *degall, *scansums;
  float *scal, *a_arr, *c_arr, *bnsum, *bnsq, *bnmean, *bnrs, *bcomb, *biasPre;
  unsigned short *wcombT, *wpreT;
  unsigned short *xb, *h1, *h2, *h3, *ts, *aggx;
  size_t agg_elems;
};

template <int F, typename To>
static void run_layer(const unsigned short* xin, To* o_ptr, float* bnout, unsigned short* hout,
                      const float* Wpre, const float* bpre, const float* Wpost, const float* bpost,
                      const float* Wlin, const float* blin, const float* gamma, const float* beta,
                      int FO, const WS& ws, hipStream_t stream) {
  const int N = N_NODES;
  const int K13 = 13 * F;
  // weight prep
  {
    dim3 g((FO + 127) / 128, (K13 + 127) / 128);
    k_wcombT<<<g, 256, 0, stream>>>(Wpost, Wlin, ws.wcombT, K13, FO, FO);
    k_wprep<<<(2 * F * F + 255) / 256, 256, 0, stream>>>(Wpre, bpre, bpost, Wlin, blin,
                                                         ws.wpreT, ws.biasPre, ws.bcomb, F, FO);
  }
  // fused pre-GEMM: ts = xin @ [W1 | W2] + [bpre | 0]
  {
    dim3 g(2 * F / 128, (N + 127) / 128);
    k_mm<unsigned short><<<g, 256, 0, stream>>>(xin, F, ws.wpreT, ws.biasPre, ws.ts, 0, N, 2 * F);
  }
  // zero BN accumulators before fused-stats post-GEMM
  hipMemsetAsync(ws.bnsum, 0, 512 * sizeof(float), stream);  // bnsum+bnsq contiguous
  // chunked: edge aggregation (4F stats) -> chunk-major virtual-13F post GEMM (stats fused for bf16)
  int NB = (int)(ws.agg_elems / (size_t)(4 * F));
  NB &= ~127;
  if (NB > N) NB = N;
  if (NB < 128) NB = 128;
  for (int c0 = 0; c0 < N; c0 += NB) {
    int nc = (N - c0 < NB) ? (N - c0) : NB;
    k_edge_agg<F><<<(nc + 3) / 4, 256, 0, stream>>>(ws.ts, ws.ptr, ws.col, ws.aggx, c0, nc);
    if (FO == 64) {
      dim3 g(1, (nc + 63) / 64);
      k_mmP<64, F, To, false><<<g, 256, 0, stream>>>(xin, ws.aggx, ws.a_arr, ws.c_arr, ws.wcombT,
                                                     ws.bcomb, o_ptr, ws.bnsum, ws.bnsq, c0, nc, NB, FO);
    } else {
      dim3 g(FO / 128, (nc + 63) / 64);
      k_mmP<128, F, To, true><<<g, 256, 0, stream>>>(xin, ws.aggx, ws.a_arr, ws.c_arr, ws.wcombT,
                                                     ws.bcomb, o_ptr, ws.bnsum, ws.bnsq, c0, nc, NB, FO);
    }
  }
  // BN + ELU
  constexpr bool is_bf = (sizeof(To) == 2);
  if constexpr (!is_bf) {
    int gs = imin((N * FO) / 1024 + 1, 1024);
    k_bn_stats_f32<64><<<gs, 256, 0, stream>>>((const float*)o_ptr, ws.bnsum, ws.bnsq);
  }
  k_bn_fin<<<1, 256, 0, stream>>>(ws.bnsum, ws.bnsq, ws.bnmean, ws.bnrs, FO);
  int total = N_NODES * FO;
  if constexpr (is_bf) {
    int ge = (total / 8 + 255) / 256;
    if (FO == 128)
      k_bn_elu_bf<128><<<ge, 256, 0, stream>>>((const unsigned short*)o_ptr, ws.bnmean, ws.bnrs, gamma, beta, hout);
    else
      k_bn_elu_bf<256><<<ge, 256, 0, stream>>>((const unsigned short*)o_ptr, ws.bnmean, ws.bnrs, gamma, beta, hout);
  } else {
    int ge = (total / 4 + 255) / 256;
    k_bn_elu_f32<64><<<ge, 256, 0, stream>>>((const float*)o_ptr, ws.bnmean, ws.bnrs, gamma, beta, hout, bnout);
  }
}

extern "C" void kernel_launch(void* const* d_in, const int* in_sizes, int n_in,
                              void* d_out, int out_size, void* d_ws, size_t ws_size,
                              hipStream_t stream) {
  const int N = N_NODES, E = N_EDGES;
  const float* x = (const float*)d_in[0];
  const int* ei = (const int*)d_in[1];
  const int* src = ei;
  const int* dst = ei + E;
  const float *Wpre[4], *bpre[4], *Wpost[4], *bpost[4], *Wlin[4], *blin[4], *gamma[4], *beta[4];
  for (int i = 0; i < 4; i++) {
    const int b = 2 + i * 8;
    Wpre[i] = (const float*)d_in[b + 0];
    bpre[i] = (const float*)d_in[b + 1];
    Wpost[i] = (const float*)d_in[b + 2];
    bpost[i] = (const float*)d_in[b + 3];
    Wlin[i] = (const float*)d_in[b + 4];
    blin[i] = (const float*)d_in[b + 5];
    gamma[i] = (const float*)d_in[b + 6];
    beta[i] = (const float*)d_in[b + 7];
  }
  const float* Wc = (const float*)d_in[34];
  const float* bcv = (const float*)d_in[35];

  // ----- workspace layout (~119 MB fixed + adaptive aggx) -----
  char* w = (char*)d_ws;
  size_t off = 0;
  auto alloc = [&](size_t bytes) -> void* {
    void* p = (void*)(w + off);
    off = (off + bytes + 255) & ~(size_t)255;
    return p;
  };
  WS ws;
  ws.ptr = (int*)alloc((N + 1) * sizeof(int));
  ws.col = (int*)alloc((size_t)E * sizeof(int));
  ws.cnt = (int*)alloc((size_t)N * sizeof(int));
  ws.degall = (int*)alloc((size_t)N * sizeof(int));
  ws.scansums = (int*)alloc((SCAN_NB + 1) * sizeof(int));
  ws.scal = (float*)alloc(16 * sizeof(float));
  ws.a_arr = (float*)alloc((size_t)N * sizeof(float));
  ws.c_arr = (float*)alloc((size_t)N * sizeof(float));
  ws.bnsum = (float*)alloc(256 * sizeof(float));
  ws.bnsq = (float*)alloc(256 * sizeof(float));
  ws.bnmean = (float*)alloc(256 * sizeof(float));
  ws.bnrs = (float*)alloc(256 * sizeof(float));
  ws.bcomb = (float*)alloc(256 * sizeof(float));
  ws.biasPre = (float*)alloc(512 * sizeof(float));
  ws.wcombT = (unsigned short*)alloc((size_t)256 * 3328 * sizeof(unsigned short));
  ws.wpreT = (unsigned short*)alloc((size_t)512 * 256 * sizeof(unsigned short));
  ws.xb = (unsigned short*)alloc((size_t)N * 128 * sizeof(unsigned short));
  ws.h1 = (unsigned short*)alloc((size_t)N * 128 * sizeof(unsigned short));
  ws.h2 = (unsigned short*)alloc((size_t)N * 256 * sizeof(unsigned short));
  ws.h3 = (unsigned short*)alloc((size_t)N * 128 * sizeof(unsigned short));
  ws.ts = (unsigned short*)alloc((size_t)N * 512 * sizeof(unsigned short));
  size_t rem = (ws_size > off) ? (ws_size - off) : 0;
  ws.agg_elems = rem / sizeof(unsigned short);
  ws.aggx = (unsigned short*)(w + off);
  unsigned short* h4 = ws.xb;  // alias: x dead after layer 1; h4 is [N,64]

  float* outp = (float*)d_out;
  float* logits = outp;              // [N,2]
  float* p4 = outp + (size_t)N * 2;  // [N,64]
  float* b4 = p4 + (size_t)N * 64;   // [N,64]
  unsigned short* o_scratch = (unsigned short*)p4;  // pre-BN scratch, overwritten by layer 4

  // ----- degree / CSR / scalars -----
  hipMemsetAsync(ws.cnt, 0, N * sizeof(int), stream);
  hipMemsetAsync(ws.degall, 0, N * sizeof(int), stream);
  hipMemsetAsync(ws.scal, 0, 16 * sizeof(float), stream);
  k_count<<<(E + 255) / 256, 256, 0, stream>>>(src, dst, ws.cnt, ws.degall);
  k_scan1<<<SCAN_NB, 1024, 0, stream>>>(ws.cnt, ws.ptr, ws.scansums);
  k_scan3<<<SCAN_NB, 1024, 0, stream>>>(ws.ptr, ws.scansums);
  hipMemsetAsync(ws.cnt, 0, N * sizeof(int), stream);
  k_fill<<<(E + 255) / 256, 256, 0, stream>>>(src, dst, ws.ptr, ws.cnt, ws.col);
  k_avglog<<<64, 256, 0, stream>>>(ws.degall, ws.scal);
  k_scalars<<<(N + 255) / 256, 256, 0, stream>>>(ws.ptr, ws.scal, ws.a_arr, ws.c_arr);
  k_cast<<<((N * 128 / 4) + 255) / 256, 256, 0, stream>>>(x, ws.xb, N * 128 / 4);

  run_layer<128, unsigned short>(ws.xb, o_scratch, nullptr, ws.h1,
                                 Wpre[0], bpre[0], Wpost[0], bpost[0], Wlin[0], blin[0], gamma[0], beta[0],
                                 128, ws, stream);
  run_layer<128, unsigned short>(ws.h1, o_scratch, nullptr, ws.h2,
                                 Wpre[1], bpre[1], Wpost[1], bpost[1], Wlin[1], blin[1], gamma[1], beta[1],
                                 256, ws, stream);
  run_layer<256, unsigned short>(ws.h2, o_scratch, nullptr, ws.h3,
                                 Wpre[2], bpre[2], Wpost[2], bpost[2], Wlin[2], blin[2], gamma[2], beta[2],
                                 128, ws, stream);
  k_add<<<((N * 128 / 8) + 255) / 256, 256, 0, stream>>>(ws.h1, ws.h3, ws.h3);  // x4 = h1 + h3 in place
  run_layer<128, float>(ws.h3, p4, b4, h4,
                        Wpre[3], bpre[3], Wpost[3], bpost[3], Wlin[3], blin[3], gamma[3], beta[3],
                        64, ws, stream);
  k_logits<<<(N + 255) / 256, 256, 0, stream>>>(h4, Wc, bcv, logits);
  (void)in_sizes; (void)n_in; (void)out_size; (void)ws_size;
}

// Round 20
// 1082.271 us; speedup vs baseline: 1.0436x; 1.0436x over previous
//
#include <hip/hip_runtime.h>
#include <math.h>

#define N_NODES 50000
#define N_EDGES 500000
#define SCAN_NB ((N_NODES + 1023) / 1024)

using bf16x8 = __attribute__((ext_vector_type(8))) short;
using f32x4  = __attribute__((ext_vector_type(4))) float;

// ---------- bf16 helpers ----------
__device__ inline float b2f(unsigned short u) {
  union { unsigned int i; float f; } v; v.i = ((unsigned int)u) << 16; return v.f;
}
__device__ inline unsigned short f2b(float f) {
  union { float f; unsigned int i; } v; v.f = f;
  unsigned int x = v.i;
  return (unsigned short)((x + 0x7fffu + ((x >> 16) & 1u)) >> 16);
}
__device__ inline unsigned int pk2(float a, float b) {
  return (unsigned int)f2b(a) | ((unsigned int)f2b(b) << 16);
}
__device__ inline void stv(unsigned short* p, float v) { *p = f2b(v); }
__device__ inline void stv(float* p, float v) { *p = v; }
__host__ __device__ inline int imin(int a, int b) { return a < b ? a : b; }

// direct global->LDS DMA, 16B per lane; lds base is wave-uniform, lane offset = lane*16
__device__ inline void gload16(const unsigned short* g, unsigned short* l) {
  __builtin_amdgcn_global_load_lds((const __attribute__((address_space(1))) unsigned int*)g,
                                   (__attribute__((address_space(3))) unsigned int*)l, 16, 0, 0);
}

// ---------------- degree / CSR ----------------
__global__ void k_count(const int* __restrict__ src, const int* __restrict__ dst,
                        int* __restrict__ cnt, int* __restrict__ degall) {
  int e = blockIdx.x * blockDim.x + threadIdx.x;
  if (e < N_EDGES) {
    atomicAdd(&cnt[dst[e]], 1);
    atomicAdd(&degall[src[e]], 1);
    atomicAdd(&degall[dst[e]], 1);
  }
}

// scan phase 1: block-local exclusive scan, block totals -> sums
__global__ __launch_bounds__(1024) void k_scan1(const int* __restrict__ cnt, int* __restrict__ ptr,
                                                int* __restrict__ sums) {
  __shared__ int buf[1024];
  int i = blockIdx.x * 1024 + threadIdx.x;
  int v = (i < N_NODES) ? cnt[i] : 0;
  buf[threadIdx.x] = v;
  __syncthreads();
  for (int off = 1; off < 1024; off <<= 1) {
    int tv = (threadIdx.x >= off) ? buf[threadIdx.x - off] : 0;
    __syncthreads();
    buf[threadIdx.x] += tv;
    __syncthreads();
  }
  if (i < N_NODES) ptr[i] = buf[threadIdx.x] - v;
  if (threadIdx.x == 1023) sums[blockIdx.x] = buf[1023];
}

// scan phase 2 (merged): each block prefix-sums block totals itself
__global__ __launch_bounds__(1024) void k_scan3(int* __restrict__ ptr, const int* __restrict__ sums) {
  __shared__ int soff;
  if (threadIdx.x == 0) {
    int acc = 0;
    for (int b = 0; b < (int)blockIdx.x; b++) acc += sums[b];
    soff = acc;
  }
  __syncthreads();
  int i = blockIdx.x * 1024 + threadIdx.x;
  if (i < N_NODES) ptr[i] += soff;
  if (blockIdx.x == SCAN_NB - 1 && threadIdx.x == 1023) ptr[N_NODES] = soff + sums[SCAN_NB - 1];
}

__global__ void k_fill(const int* __restrict__ src, const int* __restrict__ dst,
                       const int* __restrict__ ptr, int* __restrict__ cnt, int* __restrict__ col) {
  int e = blockIdx.x * blockDim.x + threadIdx.x;
  if (e < N_EDGES) {
    int d = dst[e];
    int pos = atomicAdd(&cnt[d], 1);
    col[ptr[d] + pos] = src[e];
  }
}

__global__ void k_avglog(const int* __restrict__ degall, float* __restrict__ scal) {
  __shared__ float L[256];
  float s = 0.f;
  for (int n = blockIdx.x * blockDim.x + threadIdx.x; n < N_NODES; n += gridDim.x * blockDim.x)
    s += logf((float)degall[n] + 1.0f);
  L[threadIdx.x] = s;
  __syncthreads();
  for (int o = 128; o > 0; o >>= 1) {
    if (threadIdx.x < o) L[threadIdx.x] += L[threadIdx.x + o];
    __syncthreads();
  }
  if (threadIdx.x == 0) atomicAdd(&scal[0], L[0]);
}

// avg folded in: avg = scal[0]/N
__global__ void k_scalars(const int* __restrict__ ptr, const float* __restrict__ scal,
                          float* __restrict__ a_arr, float* __restrict__ c_arr) {
  int n = blockIdx.x * blockDim.x + threadIdx.x;
  if (n < N_NODES) {
    float avg = scal[0] / (float)N_NODES;
    int d = ptr[n + 1] - ptr[n];
    float degc = fmaxf((float)d, 1.f);
    float logd = logf(degc + 1.f);
    a_arr[n] = logd / avg;
    c_arr[n] = avg / logd;
  }
}

// vectorized cast: 4 f32 -> 4 bf16 per thread
__global__ void k_cast(const float* __restrict__ x, unsigned short* __restrict__ xb, int total4) {
  int i = blockIdx.x * blockDim.x + threadIdx.x;
  if (i < total4) {
    float4 v = *(const float4*)(x + i * 4);
    *(uint2*)(xb + i * 4) = make_uint2(pk2(v.x, v.y), pk2(v.z, v.w));
  }
}

// merged weight prep: wpreT (transpose-cast), biasPre, bcomb
__global__ void k_wprep(const float* __restrict__ Wpre, const float* __restrict__ bpre,
                        const float* __restrict__ bpost, const float* __restrict__ Wlin,
                        const float* __restrict__ blin,
                        unsigned short* __restrict__ wpreT, float* __restrict__ biasPre,
                        float* __restrict__ bcomb, int F, int FO) {
  int i = blockIdx.x * blockDim.x + threadIdx.x;
  if (i < 2 * F * F) {
    int j = i / F, k = i % F;
    float v = (j < F) ? Wpre[(size_t)k * F + j] : Wpre[(size_t)(F + k) * F + (j - F)];
    wpreT[i] = f2b(v);
  }
  if (i < 2 * F) biasPre[i] = (i < F) ? bpre[i] : 0.f;
  if (i < FO) {
    float acc = blin[i];
    for (int k = 0; k < FO; k++) acc += bpost[k] * Wlin[k * FO + i];
    bcomb[i] = acc;
  }
}

// ---------------- weight GEMM: CT[c][r] = bf16( (Wpost@Wlin)[r][c] ) ----------------
__global__ __launch_bounds__(256) void k_wcombT(const float* __restrict__ A, const float* __restrict__ B,
                                                unsigned short* __restrict__ CT, int M, int Ncol, int K) {
  __shared__ float As[16][136];
  __shared__ float Bs[16][128];
  int tid = threadIdx.x;
  int row0 = blockIdx.y * 128, col0 = blockIdx.x * 128;
  int am = tid >> 1, ah = (tid & 1) * 8;
  int ty = tid >> 4, tx = tid & 15;
  float acc[8][8];
#pragma unroll
  for (int i = 0; i < 8; i++)
#pragma unroll
    for (int j = 0; j < 8; j++) acc[i][j] = 0.f;
  int arow = row0 + am;
  bool av = arow < M;
  const float* Ar = A + (size_t)arow * K;
  for (int k0 = 0; k0 < K; k0 += 16) {
    float4 a0 = make_float4(0, 0, 0, 0), a1 = make_float4(0, 0, 0, 0);
    if (av) {
      a0 = *(const float4*)(Ar + k0 + ah);
      a1 = *(const float4*)(Ar + k0 + ah + 4);
    }
    As[ah + 0][am] = a0.x; As[ah + 1][am] = a0.y; As[ah + 2][am] = a0.z; As[ah + 3][am] = a0.w;
    As[ah + 4][am] = a1.x; As[ah + 5][am] = a1.y; As[ah + 6][am] = a1.z; As[ah + 7][am] = a1.w;
#pragma unroll
    for (int i = 0; i < 2; i++) {
      int q = tid * 2 + i;
      int kk = q >> 5, j4 = (q & 31) * 4;
      int bc = col0 + j4;
      float4 b = make_float4(0, 0, 0, 0);
      if (bc < Ncol && (k0 + kk) < K) b = *(const float4*)(B + (size_t)(k0 + kk) * Ncol + bc);
      *(float4*)(&Bs[kk][j4]) = b;
    }
    __syncthreads();
#pragma unroll
    for (int kk = 0; kk < 16; kk++) {
      float av8[8], bv8[8];
#pragma unroll
      for (int i = 0; i < 8; i++) av8[i] = As[kk][ty * 8 + i];
#pragma unroll
      for (int j = 0; j < 8; j++) bv8[j] = Bs[kk][tx * 8 + j];
#pragma unroll
      for (int i = 0; i < 8; i++)
#pragma unroll
        for (int j = 0; j < 8; j++) acc[i][j] = fmaf(av8[i], bv8[j], acc[i][j]);
    }
    __syncthreads();
  }
#pragma unroll
  for (int i = 0; i < 8; i++) {
    int r = row0 + ty * 8 + i;
    if (r < M) {
#pragma unroll
      for (int j = 0; j < 8; j++) {
        int c = col0 + tx * 8 + j;
        if (c < Ncol) CT[(size_t)c * M + r] = f2b(acc[i][j]);
      }
    }
  }
}

// ---------------- m97-style MFMA GEMM (pre-GEMM): 128x128 tile, BK=32 ----------------
template <typename To>
__global__ __launch_bounds__(256) void k_mm(
    const unsigned short* __restrict__ A, int K,
    const unsigned short* __restrict__ BT,
    const float* __restrict__ bias,
    To* __restrict__ C, int n0, int M, int Ncol) {
  __shared__ unsigned short lds[2][2][4096];
  const int tid = threadIdx.x;
  const int lane = tid & 63;
  const int wid = tid >> 6;
  const int wr = wid >> 1, wc = wid & 1;
  const int row0 = blockIdx.y * 128;
  const int col0 = blockIdx.x * 128;
  const int l15 = lane & 15, lq = lane >> 4;
  const int srow = wid * 32 + (lane >> 2);
  const int scol = (lane & 3) * 8;
  const unsigned short* gA0 = A + (size_t)imin(row0 + srow, N_NODES - 1) * K + scol;
  const unsigned short* gA1 = A + (size_t)imin(row0 + srow + 16, N_NODES - 1) * K + scol;
  const unsigned short* gB0 = BT + (size_t)(col0 + srow) * K + scol;
  const unsigned short* gB1 = BT + (size_t)(col0 + srow + 16) * K + scol;

  f32x4 acc[4][4];
#pragma unroll
  for (int m = 0; m < 4; m++)
#pragma unroll
    for (int n = 0; n < 4; n++) acc[m][n] = (f32x4){0.f, 0.f, 0.f, 0.f};

  auto stage = [&](int buf, int k0) {
    gload16(gA0 + k0, &lds[buf][0][wid * 1024]);
    gload16(gA1 + k0, &lds[buf][0][wid * 1024 + 512]);
    gload16(gB0 + k0, &lds[buf][1][wid * 1024]);
    gload16(gB1 + k0, &lds[buf][1][wid * 1024 + 512]);
  };

  const int nk = K / 32;
  stage(0, 0);
  __syncthreads();
  for (int t = 0; t < nk; ++t) {
    const int cur = t & 1;
    if (t + 1 < nk) stage(cur ^ 1, (t + 1) * 32);
    bf16x8 a[4], b[4];
#pragma unroll
    for (int m = 0; m < 4; m++)
      a[m] = *(const bf16x8*)&lds[cur][0][(wr * 64 + m * 16 + l15) * 32 + lq * 8];
#pragma unroll
    for (int n = 0; n < 4; n++)
      b[n] = *(const bf16x8*)&lds[cur][1][(wc * 64 + n * 16 + l15) * 32 + lq * 8];
#pragma unroll
    for (int m = 0; m < 4; m++)
#pragma unroll
      for (int n = 0; n < 4; n++)
        acc[m][n] = __builtin_amdgcn_mfma_f32_16x16x32_bf16(a[m], b[n], acc[m][n], 0, 0, 0);
    __syncthreads();
  }
#pragma unroll
  for (int n = 0; n < 4; n++) {
    int col = col0 + wc * 64 + n * 16 + l15;
    float bv = bias ? bias[col] : 0.f;
#pragma unroll
    for (int m = 0; m < 4; m++) {
#pragma unroll
      for (int j = 0; j < 4; j++) {
        int r = row0 + wr * 64 + m * 16 + lq * 4 + j;
        if (r < M) stv(&C[(size_t)(n0 + r) * Ncol + col], acc[m][n][j] + bv);
      }
    }
  }
}

// ---------------- post-GEMM: virtual 13F A, CHUNK-MAJOR region walk, fused BN stats ----------------
// 64xNTILE tile, BK=64, XOR-swizzled LDS. Per G-chunk: 3 consecutive steps (B slices
// W2/W3/W4, A chunk L2-hot) into acc0/1/2. Epilogue: o = acc0 + an*acc1 + cn*acc2 + bias;
// if STATS: per-column sum/sumsq reduced via stride-17-padded LDS, 1 atomicAdd pair/col/block.
template <int NTILE, int F, typename To, bool STATS>
__global__ __launch_bounds__(256, 2) void k_mmP(
    const unsigned short* __restrict__ X,
    const unsigned short* __restrict__ G,
    const float* __restrict__ a_arr, const float* __restrict__ c_arr,
    const unsigned short* __restrict__ BT,
    const float* __restrict__ bias,
    To* __restrict__ C, float* __restrict__ gsum, float* __restrict__ gsq,
    int n0, int M, int Mbuf, int Ncol) {
  constexpr int K13 = 13 * F;
  constexpr int F4 = 4 * F;
  constexpr int SX = F / 64;
  constexpr int NG = F4 / 64;
  constexpr int NS = SX + 3 * NG;
  constexpr int CB = NTILE / 32;
  constexpr int NF = NTILE / 32;
  __shared__ unsigned short lds[2][(64 + NTILE) * 64];
  const int tid = threadIdx.x;
  const int lane = tid & 63;
  const int wid = tid >> 6;
  const int wr = wid >> 1, wc = wid & 1;
  const int row0 = blockIdx.y * 64;
  const int col0 = blockIdx.x * NTILE;
  const int l15 = lane & 15, lq = lane >> 4;
  const int lr8 = lane >> 3;
  const int lc8 = lane & 7;

  f32x4 acc0[2][NF], acc1[2][NF], acc2[2][NF];
#pragma unroll
  for (int m = 0; m < 2; m++)
#pragma unroll
    for (int n = 0; n < NF; n++) {
      acc0[m][n] = (f32x4){0.f, 0.f, 0.f, 0.f};
      acc1[m][n] = (f32x4){0.f, 0.f, 0.f, 0.f};
      acc2[m][n] = (f32x4){0.f, 0.f, 0.f, 0.f};
    }

  auto stage = [&](int buf, int s) {
    unsigned short* Ar = &lds[buf][0];
    unsigned short* Br = &lds[buf][64 * 64];
    int koff, akoff;
    bool isx = (s < SX);
    if (isx) {
      koff = s * 64;
      akoff = s * 64;
    } else {
      int q = s - SX;
      int tg = q / 3;
      int reg = q - 3 * tg;
      koff = F + reg * F4 + tg * 64;
      akoff = tg * 64;
    }
#pragma unroll
    for (int c = 0; c < 2; c++) {
      int r = (wid * 2 + c) * 8 + lr8;
      int gc = (lc8 ^ (r & 7)) * 8;
      const unsigned short* src;
      if (isx)
        src = X + (size_t)imin(n0 + row0 + r, N_NODES - 1) * F + akoff + gc;
      else
        src = G + (size_t)imin(row0 + r, Mbuf - 1) * F4 + akoff + gc;
      gload16(src, Ar + (wid * 2 + c) * 512);
    }
#pragma unroll
    for (int c = 0; c < CB; c++) {
      int r = (wid * CB + c) * 8 + lr8;
      int gc = (lc8 ^ (r & 7)) * 8;
      gload16(BT + (size_t)(col0 + r) * K13 + koff + gc, Br + (wid * CB + c) * 512);
    }
  };

  stage(0, 0);
  __syncthreads();
  for (int s = 0; s < NS; ++s) {
    const int cur = s & 1;
    if (s + 1 < NS) stage(cur ^ 1, s + 1);
    const unsigned short* Ar = &lds[cur][0];
    const unsigned short* Br = &lds[cur][64 * 64];
    bf16x8 a[2][2], b[2][NF];
#pragma unroll
    for (int ks = 0; ks < 2; ks++) {
#pragma unroll
      for (int m = 0; m < 2; m++) {
        int r = wr * 32 + m * 16 + l15;
        a[ks][m] = *(const bf16x8*)&Ar[r * 64 + ((lq + ks * 4) ^ (r & 7)) * 8];
      }
#pragma unroll
      for (int n = 0; n < NF; n++) {
        int r = wc * (NTILE / 2) + n * 16 + l15;
        b[ks][n] = *(const bf16x8*)&Br[r * 64 + ((lq + ks * 4) ^ (r & 7)) * 8];
      }
    }
    const int reg = (s < SX) ? 0 : (s - SX) % 3;
    if (reg == 0) {
#pragma unroll
      for (int ks = 0; ks < 2; ks++)
#pragma unroll
        for (int m = 0; m < 2; m++)
#pragma unroll
          for (int n = 0; n < NF; n++)
            acc0[m][n] = __builtin_amdgcn_mfma_f32_16x16x32_bf16(a[ks][m], b[ks][n], acc0[m][n], 0, 0, 0);
    } else if (reg == 1) {
#pragma unroll
      for (int ks = 0; ks < 2; ks++)
#pragma unroll
        for (int m = 0; m < 2; m++)
#pragma unroll
          for (int n = 0; n < NF; n++)
            acc1[m][n] = __builtin_amdgcn_mfma_f32_16x16x32_bf16(a[ks][m], b[ks][n], acc1[m][n], 0, 0, 0);
    } else {
#pragma unroll
      for (int ks = 0; ks < 2; ks++)
#pragma unroll
        for (int m = 0; m < 2; m++)
#pragma unroll
          for (int n = 0; n < NF; n++)
            acc2[m][n] = __builtin_amdgcn_mfma_f32_16x16x32_bf16(a[ks][m], b[ks][n], acc2[m][n], 0, 0, 0);
    }
    __syncthreads();
  }
  // epilogue: per-row an/cn combine + bias (+ fused column stats)
  float bs1[NF], bs2[NF];
#pragma unroll
  for (int n = 0; n < NF; n++) { bs1[n] = 0.f; bs2[n] = 0.f; }
#pragma unroll
  for (int m = 0; m < 2; m++) {
    f32x4 anv, cnv;
#pragma unroll
    for (int j = 0; j < 4; j++) {
      int g = imin(n0 + row0 + wr * 32 + m * 16 + lq * 4 + j, N_NODES - 1);
      anv[j] = a_arr[g];
      cnv[j] = c_arr[g];
    }
#pragma unroll
    for (int n = 0; n < NF; n++) {
      f32x4 v = acc0[m][n] + anv * acc1[m][n] + cnv * acc2[m][n];
      int col = col0 + wc * (NTILE / 2) + n * 16 + l15;
      float bv = bias[col];
#pragma unroll
      for (int j = 0; j < 4; j++) {
        int r = row0 + wr * 32 + m * 16 + lq * 4 + j;
        if (r < M) {
          float val = v[j] + bv;
          stv(&C[(size_t)(n0 + r) * Ncol + col], val);
          if (STATS) {
            bs1[n] += val;
            bs2[n] += val * val;
          }
        }
      }
    }
  }
  if (STATS) {
    // reduce per-column partials across lanes/waves via stride-17-padded LDS (conflict-free)
    float* red = (float*)&lds[0][0];
    const int slot = wr * 4 + lq;  // 0..7
#pragma unroll
    for (int n = 0; n < NF; n++) {
      int lcol = wc * (NTILE / 2) + n * 16 + l15;
      red[lcol * 17 + slot * 2] = bs1[n];
      red[lcol * 17 + slot * 2 + 1] = bs2[n];
    }
    __syncthreads();
    if (tid < NTILE) {
      float a1 = 0.f, a2 = 0.f;
#pragma unroll
      for (int s8 = 0; s8 < 8; s8++) {
        a1 += red[tid * 17 + s8 * 2];
        a2 += red[tid * 17 + s8 * 2 + 1];
      }
      atomicAdd(&gsum[col0 + tid], a1);
      atomicAdd(&gsq[col0 + tid], a2);
    }
  }
}

// ---------------- edge aggregation (vectorized): writes 4F rows [mean | min | max | std] ----------------
template <int F>
__global__ __launch_bounds__(256) void k_edge_agg(
    const unsigned short* __restrict__ ts,
    const int* __restrict__ ptr, const int* __restrict__ col,
    unsigned short* __restrict__ aggc, int n0, int nchunk) {
  constexpr int VU = F / 128;
  int idx = (blockIdx.x * blockDim.x + threadIdx.x) >> 6;
  int lane = threadIdx.x & 63;
  if (idx >= nchunk) return;
  int n = n0 + idx;
  if (n >= N_NODES) return;
  float S1[2 * VU], S2[2 * VU], mn[2 * VU], mx[2 * VU];
#pragma unroll
  for (int u = 0; u < 2 * VU; u++) {
    S1[u] = 0.f; S2[u] = 0.f; mn[u] = 3.4e38f; mx[u] = -3.4e38f;
  }
  int e0 = ptr[n], e1 = ptr[n + 1];
  for (int e = e0; e < e1; ++e) {
    int sidx = col[e];
    const unsigned int* sr = (const unsigned int*)(ts + (size_t)sidx * 2 * F + F);
#pragma unroll
    for (int u = 0; u < VU; u++) {
      unsigned int v = sr[lane + 64 * u];
      float f0 = b2f((unsigned short)(v & 0xffff));
      float f1 = b2f((unsigned short)(v >> 16));
      S1[2 * u] += f0; S2[2 * u] += f0 * f0;
      mn[2 * u] = fminf(mn[2 * u], f0); mx[2 * u] = fmaxf(mx[2 * u], f0);
      S1[2 * u + 1] += f1; S2[2 * u + 1] += f1 * f1;
      mn[2 * u + 1] = fminf(mn[2 * u + 1], f1); mx[2 * u + 1] = fmaxf(mx[2 * u + 1], f1);
    }
  }
  int d = e1 - e0;
  const unsigned int* tr = (const unsigned int*)(ts + (size_t)n * 2 * F);
  unsigned int* ob = (unsigned int*)(aggc + (size_t)idx * 4 * F);
  constexpr int UB = 64 * VU;
#pragma unroll
  for (int u = 0; u < VU; u++) {
    int ui = lane + 64 * u;
    float mean0, mean1, lo0, lo1, hi0, hi1, sd0, sd1;
    if (d > 0) {
      float inv = 1.f / (float)d;
      unsigned int tv = tr[ui];
      float t0 = b2f((unsigned short)(tv & 0xffff));
      float t1 = b2f((unsigned short)(tv >> 16));
      float ms0 = S1[2 * u] * inv, ms1 = S1[2 * u + 1] * inv;
      sd0 = sqrtf(fmaxf(S2[2 * u] * inv - ms0 * ms0, 0.f) + 1e-5f);
      sd1 = sqrtf(fmaxf(S2[2 * u + 1] * inv - ms1 * ms1, 0.f) + 1e-5f);
      mean0 = t0 + ms0; mean1 = t1 + ms1;
      lo0 = t0 + mn[2 * u]; lo1 = t1 + mn[2 * u + 1];
      hi0 = t0 + mx[2 * u]; hi1 = t1 + mx[2 * u + 1];
    } else {
      mean0 = mean1 = lo0 = lo1 = hi0 = hi1 = 0.f;
      sd0 = sd1 = sqrtf(1e-5f);
    }
    unsigned int* o1 = ob + ui;
    o1[0] = pk2(mean0, mean1);
    o1[UB] = pk2(lo0, lo1);
    o1[2 * UB] = pk2(hi0, hi1);
    o1[3 * UB] = pk2(sd0, sd1);
  }
}

// ---------------- BN stats (f32 path, layer 4 only) ----------------
template <int FO>
__global__ __launch_bounds__(256) void k_bn_stats_f32(const float* __restrict__ o,
                                                      float* __restrict__ gsum, float* __restrict__ gsq) {
  constexpr int TOTAL = N_NODES * FO;
  float s1[4], s2[4];
#pragma unroll
  for (int j = 0; j < 4; j++) { s1[j] = 0.f; s2[j] = 0.f; }
  const int stride = gridDim.x * 1024;
  for (int base = blockIdx.x * 1024 + threadIdx.x * 4; base < TOTAL; base += stride) {
    float4 v = *(const float4*)(o + base);
    s1[0] += v.x; s2[0] += v.x * v.x;
    s1[1] += v.y; s2[1] += v.y * v.y;
    s1[2] += v.z; s2[2] += v.z * v.z;
    s1[3] += v.w; s2[3] += v.w * v.w;
  }
  __shared__ float L1[1024], L2[1024];
#pragma unroll
  for (int j = 0; j < 4; j++) {
    L1[threadIdx.x * 4 + j] = s1[j];
    L2[threadIdx.x * 4 + j] = s2[j];
  }
  __syncthreads();
  int c = threadIdx.x;
  if (c < FO) {
    float a1 = 0.f, a2 = 0.f;
    for (int i = c; i < 1024; i += FO) { a1 += L1[i]; a2 += L2[i]; }
    atomicAdd(&gsum[c], a1);
    atomicAdd(&gsq[c], a2);
  }
}

__global__ void k_bn_fin(const float* bnsum, const float* bnsq, float* bnmean, float* bnrs, int FO) {
  int c = threadIdx.x;
  if (c < FO) {
    float mean = bnsum[c] / (float)N_NODES;
    float var = bnsq[c] / (float)N_NODES - mean * mean;
    bnmean[c] = mean;
    bnrs[c] = rsqrtf(var + 1e-5f);
  }
}

// ---------------- BN+ELU (vectorized) ----------------
template <int FO>
__global__ __launch_bounds__(256) void k_bn_elu_bf(const unsigned short* __restrict__ o,
                                                   const float* __restrict__ mean, const float* __restrict__ rs,
                                                   const float* __restrict__ gamma, const float* __restrict__ beta,
                                                   unsigned short* __restrict__ h) {
  constexpr int TOTAL = N_NODES * FO;
  int base = (blockIdx.x * blockDim.x + threadIdx.x) * 8;
  if (base >= TOTAL) return;
  int c0 = base % FO;
  uint4 v = *(const uint4*)(o + base);
  const unsigned int* u = (const unsigned int*)&v;
  unsigned int outw[4];
#pragma unroll
  for (int w = 0; w < 4; w++) {
    int c = c0 + 2 * w;
    float f0 = b2f((unsigned short)(u[w] & 0xffff));
    float f1 = b2f((unsigned short)(u[w] >> 16));
    float y0 = gamma[c] * (f0 - mean[c]) * rs[c] + beta[c];
    float y1 = gamma[c + 1] * (f1 - mean[c + 1]) * rs[c + 1] + beta[c + 1];
    y0 = y0 > 0.f ? y0 : expm1f(y0);
    y1 = y1 > 0.f ? y1 : expm1f(y1);
    outw[w] = pk2(y0, y1);
  }
  *(uint4*)(h + base) = *(uint4*)outw;
}

template <int FO>
__global__ __launch_bounds__(256) void k_bn_elu_f32(const float* __restrict__ o,
                                                    const float* __restrict__ mean, const float* __restrict__ rs,
                                                    const float* __restrict__ gamma, const float* __restrict__ beta,
                                                    unsigned short* __restrict__ h, float* __restrict__ bnout) {
  constexpr int TOTAL = N_NODES * FO;
  int base = (blockIdx.x * blockDim.x + threadIdx.x) * 4;
  if (base >= TOTAL) return;
  int c = base % FO;
  float4 v = *(const float4*)(o + base);
  float y0 = gamma[c] * (v.x - mean[c]) * rs[c] + beta[c];
  float y1 = gamma[c + 1] * (v.y - mean[c + 1]) * rs[c + 1] + beta[c + 1];
  float y2 = gamma[c + 2] * (v.z - mean[c + 2]) * rs[c + 2] + beta[c + 2];
  float y3 = gamma[c + 3] * (v.w - mean[c + 3]) * rs[c + 3] + beta[c + 3];
  if (bnout) *(float4*)(bnout + base) = make_float4(y0, y1, y2, y3);
  unsigned int o0 = pk2(y0 > 0.f ? y0 : expm1f(y0), y1 > 0.f ? y1 : expm1f(y1));
  unsigned int o1 = pk2(y2 > 0.f ? y2 : expm1f(y2), y3 > 0.f ? y3 : expm1f(y3));
  *(uint2*)(h + base) = make_uint2(o0, o1);
}

// ---------------- misc ----------------
// vectorized add: 8 bf16 per thread
__global__ void k_add(const unsigned short* __restrict__ a, const unsigned short* __restrict__ b,
                      unsigned short* __restrict__ c) {
  int i = blockIdx.x * blockDim.x + threadIdx.x;
  if (i < (N_NODES * 128) / 8) {
    uint4 va = *(const uint4*)(a + i * 8);
    uint4 vb = *(const uint4*)(b + i * 8);
    const unsigned int* ua = (const unsigned int*)&va;
    const unsigned int* ub = (const unsigned int*)&vb;
    unsigned int outw[4];
#pragma unroll
    for (int w = 0; w < 4; w++) {
      float a0 = b2f((unsigned short)(ua[w] & 0xffff)) + b2f((unsigned short)(ub[w] & 0xffff));
      float a1 = b2f((unsigned short)(ua[w] >> 16)) + b2f((unsigned short)(ub[w] >> 16));
      outw[w] = pk2(a0, a1);
    }
    *(uint4*)(c + i * 8) = *(uint4*)outw;
  }
}

// vectorized logits: uint4 loads of h4 row
__global__ void k_logits(const unsigned short* __restrict__ h4, const float* __restrict__ Wc,
                         const float* __restrict__ bc, float* __restrict__ out) {
  int n = blockIdx.x * blockDim.x + threadIdx.x;
  if (n < N_NODES) {
    float acc0 = bc[0], acc1 = bc[1];
    const uint4* hr = (const uint4*)(h4 + (size_t)n * 64);
#pragma unroll
    for (int q = 0; q < 8; q++) {
      uint4 v = hr[q];
      const unsigned int* u = (const unsigned int*)&v;
#pragma unroll
      for (int w = 0; w < 4; w++) {
        int k = q * 8 + w * 2;
        float f0 = b2f((unsigned short)(u[w] & 0xffff));
        float f1 = b2f((unsigned short)(u[w] >> 16));
        acc0 += f0 * Wc[k * 2 + 0] + f1 * Wc[(k + 1) * 2 + 0];
        acc1 += f0 * Wc[k * 2 + 1] + f1 * Wc[(k + 1) * 2 + 1];
      }
    }
    out[n * 2 + 0] = acc0;
    out[n * 2 + 1] = acc1;
  }
}

// ---------------- driver ----------------
struct WS {
  int *ptr, *col, *cnt, *degall, *scansums;
  float *scal, *a_arr, *c_arr, *bnsum, *bnsq, *bnmean, *bnrs, *bcomb, *biasPre;
  unsigned short *wcombT, *wpreT;
  unsigned short *xb, *h1, *h2, *h3, *ts, *aggx;
  size_t agg_elems;
};

template <int F, typename To>
static void run_layer(const unsigned short* xin, To* o_ptr, float* bnout, unsigned short* hout,
                      const float* Wpre, const float* bpre, const float* Wpost, const float* bpost,
                      const float* Wlin, const float* blin, const float* gamma, const float* beta,
                      int FO, const WS& ws, hipStream_t stream) {
  const int N = N_NODES;
  const int K13 = 13 * F;
  // weight prep
  {
    dim3 g((FO + 127) / 128, (K13 + 127) / 128);
    k_wcombT<<<g, 256, 0, stream>>>(Wpost, Wlin, ws.wcombT, K13, FO, FO);
    k_wprep<<<(2 * F * F + 255) / 256, 256, 0, stream>>>(Wpre, bpre, bpost, Wlin, blin,
                                                         ws.wpreT, ws.biasPre, ws.bcomb, F, FO);
  }
  // fused pre-GEMM: ts = xin @ [W1 | W2] + [bpre | 0]
  {
    dim3 g(2 * F / 128, (N + 127) / 128);
    k_mm<unsigned short><<<g, 256, 0, stream>>>(xin, F, ws.wpreT, ws.biasPre, ws.ts, 0, N, 2 * F);
  }
  // zero BN accumulators before fused-stats post-GEMM
  hipMemsetAsync(ws.bnsum, 0, 512 * sizeof(float), stream);  // bnsum+bnsq contiguous
  // chunked: edge aggregation (4F stats) -> chunk-major virtual-13F post GEMM (stats fused for bf16)
  int NB = (int)(ws.agg_elems / (size_t)(4 * F));
  NB &= ~127;
  if (NB > N) NB = N;
  if (NB < 128) NB = 128;
  for (int c0 = 0; c0 < N; c0 += NB) {
    int nc = (N - c0 < NB) ? (N - c0) : NB;
    k_edge_agg<F><<<(nc + 3) / 4, 256, 0, stream>>>(ws.ts, ws.ptr, ws.col, ws.aggx, c0, nc);
    if (FO == 64) {
      dim3 g(1, (nc + 63) / 64);
      k_mmP<64, F, To, false><<<g, 256, 0, stream>>>(xin, ws.aggx, ws.a_arr, ws.c_arr, ws.wcombT,
                                                     ws.bcomb, o_ptr, ws.bnsum, ws.bnsq, c0, nc, NB, FO);
    } else {
      dim3 g(FO / 128, (nc + 63) / 64);
      k_mmP<128, F, To, true><<<g, 256, 0, stream>>>(xin, ws.aggx, ws.a_arr, ws.c_arr, ws.wcombT,
                                                     ws.bcomb, o_ptr, ws.bnsum, ws.bnsq, c0, nc, NB, FO);
    }
  }
  // BN + ELU
  constexpr bool is_bf = (sizeof(To) == 2);
  if constexpr (!is_bf) {
    int gs = imin((N * FO) / 1024 + 1, 1024);
    k_bn_stats_f32<64><<<gs, 256, 0, stream>>>((const float*)o_ptr, ws.bnsum, ws.bnsq);
  }
  k_bn_fin<<<1, 256, 0, stream>>>(ws.bnsum, ws.bnsq, ws.bnmean, ws.bnrs, FO);
  int total = N_NODES * FO;
  if constexpr (is_bf) {
    int ge = (total / 8 + 255) / 256;
    if (FO == 128)
      k_bn_elu_bf<128><<<ge, 256, 0, stream>>>((const unsigned short*)o_ptr, ws.bnmean, ws.bnrs, gamma, beta, hout);
    else
      k_bn_elu_bf<256><<<ge, 256, 0, stream>>>((const unsigned short*)o_ptr, ws.bnmean, ws.bnrs, gamma, beta, hout);
  } else {
    int ge = (total / 4 + 255) / 256;
    k_bn_elu_f32<64><<<ge, 256, 0, stream>>>((const float*)o_ptr, ws.bnmean, ws.bnrs, gamma, beta, hout, bnout);
  }
}

extern "C" void kernel_launch(void* const* d_in, const int* in_sizes, int n_in,
                              void* d_out, int out_size, void* d_ws, size_t ws_size,
                              hipStream_t stream) {
  const int N = N_NODES, E = N_EDGES;
  const float* x = (const float*)d_in[0];
  const int* ei = (const int*)d_in[1];
  const int* src = ei;
  const int* dst = ei + E;
  const float *Wpre[4], *bpre[4], *Wpost[4], *bpost[4], *Wlin[4], *blin[4], *gamma[4], *beta[4];
  for (int i = 0; i < 4; i++) {
    const int b = 2 + i * 8;
    Wpre[i] = (const float*)d_in[b + 0];
    bpre[i] = (const float*)d_in[b + 1];
    Wpost[i] = (const float*)d_in[b + 2];
    bpost[i] = (const float*)d_in[b + 3];
    Wlin[i] = (const float*)d_in[b + 4];
    blin[i] = (const float*)d_in[b + 5];
    gamma[i] = (const float*)d_in[b + 6];
    beta[i] = (const float*)d_in[b + 7];
  }
  const float* Wc = (const float*)d_in[34];
  const float* bcv = (const float*)d_in[35];

  // ----- workspace layout (~119 MB fixed + adaptive aggx) -----
  char* w = (char*)d_ws;
  size_t off = 0;
  auto alloc = [&](size_t bytes) -> void* {
    void* p = (void*)(w + off);
    off = (off + bytes + 255) & ~(size_t)255;
    return p;
  };
  WS ws;
  ws.ptr = (int*)alloc((N + 1) * sizeof(int));
  ws.col = (int*)alloc((size_t)E * sizeof(int));
  ws.cnt = (int*)alloc((size_t)N * sizeof(int));
  ws.degall = (int*)alloc((size_t)N * sizeof(int));
  ws.scansums = (int*)alloc((SCAN_NB + 1) * sizeof(int));
  ws.scal = (float*)alloc(16 * sizeof(float));
  ws.a_arr = (float*)alloc((size_t)N * sizeof(float));
  ws.c_arr = (float*)alloc((size_t)N * sizeof(float));
  ws.bnsum = (float*)alloc(256 * sizeof(float));
  ws.bnsq = (float*)alloc(256 * sizeof(float));
  ws.bnmean = (float*)alloc(256 * sizeof(float));
  ws.bnrs = (float*)alloc(256 * sizeof(float));
  ws.bcomb = (float*)alloc(256 * sizeof(float));
  ws.biasPre = (float*)alloc(512 * sizeof(float));
  ws.wcombT = (unsigned short*)alloc((size_t)256 * 3328 * sizeof(unsigned short));
  ws.wpreT = (unsigned short*)alloc((size_t)512 * 256 * sizeof(unsigned short));
  ws.xb = (unsigned short*)alloc((size_t)N * 128 * sizeof(unsigned short));
  ws.h1 = (unsigned short*)alloc((size_t)N * 128 * sizeof(unsigned short));
  ws.h2 = (unsigned short*)alloc((size_t)N * 256 * sizeof(unsigned short));
  ws.h3 = (unsigned short*)alloc((size_t)N * 128 * sizeof(unsigned short));
  ws.ts = (unsigned short*)alloc((size_t)N * 512 * sizeof(unsigned short));
  size_t rem = (ws_size > off) ? (ws_size - off) : 0;
  ws.agg_elems = rem / sizeof(unsigned short);
  ws.aggx = (unsigned short*)(w + off);
  unsigned short* h4 = ws.xb;  // alias: x dead after layer 1; h4 is [N,64]

  float* outp = (float*)d_out;
  float* logits = outp;              // [N,2]
  float* p4 = outp + (size_t)N * 2;  // [N,64]
  float* b4 = p4 + (size_t)N * 64;   // [N,64]
  unsigned short* o_scratch = (unsigned short*)p4;  // pre-BN scratch, overwritten by layer 4

  // ----- degree / CSR / scalars -----
  hipMemsetAsync(ws.cnt, 0, N * sizeof(int), stream);
  hipMemsetAsync(ws.degall, 0, N * sizeof(int), stream);
  hipMemsetAsync(ws.scal, 0, 16 * sizeof(float), stream);
  k_count<<<(E + 255) / 256, 256, 0, stream>>>(src, dst, ws.cnt, ws.degall);
  k_scan1<<<SCAN_NB, 1024, 0, stream>>>(ws.cnt, ws.ptr, ws.scansums);
  k_scan3<<<SCAN_NB, 1024, 0, stream>>>(ws.ptr, ws.scansums);
  hipMemsetAsync(ws.cnt, 0, N * sizeof(int), stream);
  k_fill<<<(E + 255) / 256, 256, 0, stream>>>(src, dst, ws.ptr, ws.cnt, ws.col);
  k_avglog<<<64, 256, 0, stream>>>(ws.degall, ws.scal);
  k_scalars<<<(N + 255) / 256, 256, 0, stream>>>(ws.ptr, ws.scal, ws.a_arr, ws.c_arr);
  k_cast<<<((N * 128 / 4) + 255) / 256, 256, 0, stream>>>(x, ws.xb, N * 128 / 4);

  run_layer<128, unsigned short>(ws.xb, o_scratch, nullptr, ws.h1,
                                 Wpre[0], bpre[0], Wpost[0], bpost[0], Wlin[0], blin[0], gamma[0], beta[0],
                                 128, ws, stream);
  run_layer<128, unsigned short>(ws.h1, o_scratch, nullptr, ws.h2,
                                 Wpre[1], bpre[1], Wpost[1], bpost[1], Wlin[1], blin[1], gamma[1], beta[1],
                                 256, ws, stream);
  run_layer<256, unsigned short>(ws.h2, o_scratch, nullptr, ws.h3,
                                 Wpre[2], bpre[2], Wpost[2], bpost[2], Wlin[2], blin[2], gamma[2], beta[2],
                                 128, ws, stream);
  k_add<<<((N * 128 / 8) + 255) / 256, 256, 0, stream>>>(ws.h1, ws.h3, ws.h3);  // x4 = h1 + h3 in place
  run_layer<128, float>(ws.h3, p4, b4, h4,
                        Wpre[3], bpre[3], Wpost[3], bpost[3], Wlin[3], blin[3], gamma[3], beta[3],
                        64, ws, stream);
  k_logits<<<(N + 255) / 256, 256, 0, stream>>>(h4, Wc, bcv, logits);
  (void)in_sizes; (void)n_in; (void)out_size; (void)ws_size;
}